// Round 8
// baseline (130.169 us; speedup 1.0000x reference)
//
#include <hip/hip_runtime.h>
#include <math.h>

#define CC 256
#define NPIX 4096
#define BATCH 4
#define LOG2E 1.4426950408889634f

typedef __attribute__((ext_vector_type(8)))  short short8;
typedef __attribute__((ext_vector_type(8)))  int   int32x8;
typedef __attribute__((ext_vector_type(16))) float f32x16;

union FragU { short8 v; short s[8]; unsigned u[4]; uint2 d[2]; };
union V8  { uint4 q[2]; int32x8 iv; };
union B8  { unsigned u[8]; int32x8 iv; };

__device__ inline unsigned pkbf(float a, float b) {   // pack 2 floats -> 2 bf16 (RNE)
    unsigned x = __float_as_uint(a), y = __float_as_uint(b);
    x = (x + 0x7FFFu + ((x >> 16) & 1u)) >> 16;
    y = (y + 0x7FFFu + ((y >> 16) & 1u)) & 0xFFFF0000u;
    return x | y;
}
__device__ inline unsigned short bf1(float a) {
    unsigned x = __float_as_uint(a);
    return (unsigned short)((x + 0x7FFFu + ((x >> 16) & 1u)) >> 16);
}
__device__ inline float ex2(float x) { return __builtin_amdgcn_exp2f(x); }
__device__ inline unsigned pk4fp8(float a, float b, float c, float d) {
    int r = __builtin_amdgcn_cvt_pk_fp8_f32(a, b, 0, false);
    r = __builtin_amdgcn_cvt_pk_fp8_f32(c, d, r, true);
    return (unsigned)r;
}
__device__ inline f32x16 zero16() {
    f32x16 v;
    #pragma unroll
    for (int i = 0; i < 16; ++i) v[i] = 0.0f;
    return v;
}
__device__ inline f32x16 mfma32(short8 a, short8 b, f32x16 c) {
    return __builtin_amdgcn_mfma_f32_32x32x16_bf16(a, b, c, 0, 0, 0);
}
// MX-scaled fp8 K=64, identity scales (e8m0 0x7F = 2^0)
__device__ inline f32x16 mfma64s(int32x8 a, int32x8 b, f32x16 c) {
    return __builtin_amdgcn_mfma_scale_f32_32x32x64_f8f6f4(
        a, b, c, 0 /*cbsz: fp8*/, 0 /*blgp: fp8*/, 0, 0x7F, 0, 0x7F);
}

// ---------------------------------------------------------------------------
// prep_w: 40 blocks, W-pack only.
// Packs W -> Wfrag[gs][lane][8] in MFMA B-frag order.
// ---------------------------------------------------------------------------
__global__ __launch_bounds__(256, 2) void prep_w(
    const float* __restrict__ Wq, const float* __restrict__ Wk,
    const float* __restrict__ Wv, unsigned short* __restrict__ Wfrag)
{
    const int t = threadIdx.x;
    const int wb = blockIdx.x;           // 0..39
    const int l = t & 63, rr = t >> 6;   // rr 0..3
    #pragma unroll
    for (int e = 0; e < 4; ++e) {
        int gs = wb * 4 + e;             // 0..159
        int g = gs >> 4, s = gs & 15;
        const float* src; float scale = 1.0f; int oc0 = 0;
        if (g == 0)      { src = Wq; scale = LOG2E; }
        else if (g == 1) { src = Wk; }
        else             { src = Wv; oc0 = (g - 2) * 32; }
        int row = oc0 + (l & 31);
        int kb2 = 16 * s + 8 * (l >> 5) + rr * 2;
        float v0 = src[(size_t)row * CC + kb2] * scale;
        float v1 = src[(size_t)row * CC + kb2 + 1] * scale;
        *(unsigned*)(Wfrag + (size_t)(gs * 64 + l) * 8 + rr * 2) = pkbf(v0, v1);
    }
}

// ---------------------------------------------------------------------------
// proj: round-6 shape (measured faster than the 32-px split of round 7).
// ONE block per (batch, 64-px tile): 256 blocks x 640 thr (10 waves).
// Phase 0: 512 threads transpose x (f32 [C][N]) into bf16 LDS xls[64][260].
// Wave w = ocg (0=q 1=k 2..9 = V cg) then runs the MFMA projection.
// qT/kT bf16 (q pre-scaled log2e); V written fp8-e4m3 into
// vI[b][j64][cg][lane: jhalf*32+c][32B] (byte = j&31 — K=64 A-frag order).
// ---------------------------------------------------------------------------
__global__ __launch_bounds__(640, 2) void proj_mfma(
    const float* __restrict__ x, const unsigned short* __restrict__ Wfrag,
    const float* __restrict__ mask,
    const float* __restrict__ bq, const float* __restrict__ bk,
    const float* __restrict__ bv,
    unsigned short* __restrict__ qT, unsigned short* __restrict__ kT,
    unsigned char* __restrict__ vI)
{
    __shared__ unsigned short xls[64 * 260];
    const int t = threadIdx.x;
    const int w = t >> 6, l = t & 63, L = l & 31, h = l >> 5;
    const int bid = blockIdx.x;
    const int b    = (bid >> 1) & 3;                 // XCD-pinned by batch
    const int u    = ((bid >> 3) << 1) | (bid & 1);  // 0..63
    const int p0   = u * 64;
    const int ocg  = w;                              // 0=q 1=k 2..9 = v cg

    // ---- phase 0: x -> bf16 LDS transpose (512 threads) ----
    if (t < 512) {
        const int pg = t & 15;               // 4-px group
        const int cb = (t >> 4) * 2;         // channel pair base (0..62 even)
        const float* xb = x + (size_t)b * CC * NPIX + p0 + pg * 4;
        #pragma unroll
        for (int k = 0; k < 4; ++k) {
            int c = cb + 64 * k;
            float4 v0 = *(const float4*)(xb + (size_t)c * NPIX);
            float4 v1 = *(const float4*)(xb + (size_t)(c + 1) * NPIX);
            *(unsigned*)&xls[(pg * 4 + 0) * 260 + c] = pkbf(v0.x, v1.x);
            *(unsigned*)&xls[(pg * 4 + 1) * 260 + c] = pkbf(v0.y, v1.y);
            *(unsigned*)&xls[(pg * 4 + 2) * 260 + c] = pkbf(v0.z, v1.z);
            *(unsigned*)&xls[(pg * 4 + 3) * 260 + c] = pkbf(v0.w, v1.w);
        }
    }

    FragU wf[16];
    const unsigned short* wp = Wfrag + (size_t)(ocg * 16 * 64 + l) * 8;
    #pragma unroll
    for (int s = 0; s < 16; ++s) wf[s].v = *(const short8*)(wp + s * 512);

    float bcol;
    if (ocg == 0)      bcol = bq[L] * LOG2E;
    else if (ocg == 1) bcol = bk[L];
    else               bcol = bv[(ocg - 2) * 32 + L];
    const float* mb = mask + (size_t)b * NPIX;
    __syncthreads();

    #pragma unroll
    for (int mt = 0; mt < 2; ++mt) {
        const int pp = 32 * mt;
        f32x16 acc = zero16();
        #pragma unroll
        for (int s = 0; s < 16; ++s) {
            FragU af;
            const unsigned short* ap = &xls[(pp + L) * 260 + 16 * s + 8 * h];
            af.d[0] = *(const uint2*)(ap);
            af.d[1] = *(const uint2*)(ap + 4);
            acc = mfma32(af.v, wf[s].v, acc);
        }
        if (ocg < 2) {
            unsigned short* dst = (ocg ? kT : qT) + (size_t)b * NPIX * 32;
            #pragma unroll
            for (int r = 0; r < 16; ++r) {
                int prow = (r & 3) + 8 * (r >> 2) + 4 * h;
                float mv = mb[p0 + pp + prow];
                dst[(size_t)(p0 + pp + prow) * 32 + L] = bf1((acc[r] + bcol) * mv);
            }
        } else {
            const int cg = ocg - 2;
            const int jb32 = p0 + pp;                // 32-j block base
            // dword m holds j-rows 8m+4h+{0..3} -> byte offset 8m+4h
            unsigned char* dst = vI + (size_t)b * (1 << 20)
                + (size_t)(jb32 >> 6) * 16384 + cg * 2048
                + (((jb32 >> 5) & 1) * 32 + L) * 32 + 4 * h;
            #pragma unroll
            for (int m = 0; m < 4; ++m) {
                unsigned pk = pk4fp8(acc[4*m]   + bcol, acc[4*m+1] + bcol,
                                     acc[4*m+2] + bcol, acc[4*m+3] + bcol);
                *(unsigned*)(dst + 8 * m) = pk;
            }
        }
    }
}

// ---------------------------------------------------------------------------
// attn: FUSED 8-wave blocks (512 thr, 64 i-rows). Waves w and w+4 process
// different 32-row i-sub-tiles but the SAME j-quarter (w&3): their K/V loads
// are byte-identical, and a per-iteration barrier (placed after load issue,
// so the stall overlaps load/MFMA latency) keeps the pair time-aligned so
// the second wave hits in L1 — halving L2 read traffic vs two independent
// 4-wave blocks per CU. Per-wave schedule/math unchanged from round 6
// (rotated schedule, hysteresis 8, per-half l_run, setprio MFMA clusters).
// ---------------------------------------------------------------------------
__global__ __launch_bounds__(512, 2) void attn_mfma(
    const unsigned short* __restrict__ qT, const unsigned short* __restrict__ kT,
    const unsigned char* __restrict__ vI, const float* __restrict__ x,
    const float* __restrict__ gamma, float* __restrict__ out)
{
    __shared__ float mls[8][32];
    __shared__ float lls[2][8][32];
    __shared__ float obuf[8][2048];

    const int t = threadIdx.x;
    const int w = t >> 6, l = t & 63, L = l & 31, h = l >> 5;
    const int bid = blockIdx.x;
    const int b    = (bid >> 1) & 3;                 // XCD-pinned by batch
    const int it64 = (bid >> 3) * 2 + (bid & 1);     // 0..63 (64-row i-tile)
    const int pair = w >> 2;                         // i-sub-tile 0/1
    const int jq   = w & 3;                          // j-quarter (shared by pair)
    const int i0   = it64 * 64 + pair * 32;

    const unsigned short* qrow = qT + ((size_t)b * NPIX + i0 + L) * 32 + 8 * h;
    short8 qf0 = *(const short8*)(qrow);
    short8 qf1 = *(const short8*)(qrow + 16);

    const int jbase = jq * 1024;
    // K stream: one byte pointer, advanced 4096 B/iter; imm offsets 0/32/2048/2080
    const unsigned char* kp = (const unsigned char*)kT
        + (size_t)b * NPIX * 64 + (size_t)jbase * 64 + (size_t)L * 64 + 16 * h;
    short8 ka0 = *(const short8*)(kp);
    short8 ka1 = *(const short8*)(kp + 32);
    short8 kb0 = *(const short8*)(kp + 2048);
    short8 kb1 = *(const short8*)(kp + 2080);
    kp += 4096;
    // V stream: lane l reads its 32B at vp + cg*2048; advance 16384 B/iter
    const unsigned char* vp = vI + (size_t)b * (1 << 20)
        + (size_t)(jbase >> 6) * 16384 + (size_t)l * 32;

    f32x16 acc[8];
    #pragma unroll
    for (int cg = 0; cg < 8; ++cg) acc[cg] = zero16();
    float m_run = -INFINITY, l_run = 0.0f;
    bool warm = false;   // first rescale trigger has acc==0: skip the 128-mul pass

    // ---- prologue: S(0) ----
    f32x16 s0 = zero16(), s1 = zero16();
    __builtin_amdgcn_s_setprio(1);
    s0 = mfma32(ka0, qf0, s0);
    s0 = mfma32(ka1, qf1, s0);
    s1 = mfma32(kb0, qf0, s1);
    s1 = mfma32(kb1, qf1, s1);
    __builtin_amdgcn_s_setprio(0);

    for (int itr = 0; itr < 16; ++itr) {
        // ---- K load (n+1) — consumed by S(n+1) at the bottom of THIS iter.
        //      (last iter reads past kT: valid ws mem, result discarded)
        ka0 = *(const short8*)(kp);
        ka1 = *(const short8*)(kp + 32);
        kb0 = *(const short8*)(kp + 2048);
        kb1 = *(const short8*)(kp + 2080);
        kp += 4096;

        // ---- V loads, first half (cg 0..3) ----
        V8 vv[4];
        #pragma unroll
        for (int cg = 0; cg < 4; ++cg) {
            vv[cg].q[0] = *(const uint4*)(vp + cg * 2048);
            vv[cg].q[1] = *(const uint4*)(vp + cg * 2048 + 16);
        }

        // ---- pair-alignment barrier: loads are in flight, S(n) is draining;
        //      keeps waves w / w+4 time-aligned so their identical K/V
        //      addresses dedupe in L1 instead of double-hitting L2.
        __syncthreads();

        // ---- row max: max3 chains, shfl syncs the lane pair (same i) ----
        float t0 = fmaxf(fmaxf(s0[0],  s0[4]),  s0[8]);
        float t1 = fmaxf(fmaxf(s0[1],  s0[5]),  s0[9]);
        float t2 = fmaxf(fmaxf(s0[2],  s0[6]),  s0[10]);
        float t3 = fmaxf(fmaxf(s0[3],  s0[7]),  s0[11]);
        t0 = fmaxf(fmaxf(t0, s0[12]), s1[0]);
        t1 = fmaxf(fmaxf(t1, s0[13]), s1[1]);
        t2 = fmaxf(fmaxf(t2, s0[14]), s1[2]);
        t3 = fmaxf(fmaxf(t3, s0[15]), s1[3]);
        t0 = fmaxf(fmaxf(t0, s1[4]),  s1[8]);
        t1 = fmaxf(fmaxf(t1, s1[5]),  s1[9]);
        t2 = fmaxf(fmaxf(t2, s1[6]),  s1[10]);
        t3 = fmaxf(fmaxf(t3, s1[7]),  s1[11]);
        t0 = fmaxf(t0, s1[12]);
        t1 = fmaxf(t1, s1[13]);
        t2 = fmaxf(t2, s1[14]);
        t3 = fmaxf(t3, s1[15]);
        float tmax = fmaxf(fmaxf(fmaxf(t0, t1), t2), t3);
        tmax = fmaxf(tmax, __shfl_xor(tmax, 32));

        if (__ballot(tmax > m_run + 8.0f)) {
            float m_new = fmaxf(m_run, tmax);
            if (warm) {
                float alpha = ex2(m_run - m_new);
                l_run *= alpha;
                #pragma unroll
                for (int cg = 0; cg < 8; ++cg)
                    #pragma unroll
                    for (int r = 0; r < 16; ++r) acc[cg][r] *= alpha;
            }
            m_run = m_new;
            warm = true;
        }

        float z0 = 0, z1 = 0, z2 = 0, z3 = 0;
        #pragma unroll
        for (int r = 0; r < 16; r += 4) {
            s0[r]   = ex2(s0[r]   - m_run); z0 += s0[r];
            s0[r+1] = ex2(s0[r+1] - m_run); z1 += s0[r+1];
            s0[r+2] = ex2(s0[r+2] - m_run); z2 += s0[r+2];
            s0[r+3] = ex2(s0[r+3] - m_run); z3 += s0[r+3];
        }
        #pragma unroll
        for (int r = 0; r < 16; r += 4) {
            s1[r]   = ex2(s1[r]   - m_run); z0 += s1[r];
            s1[r+1] = ex2(s1[r+1] - m_run); z1 += s1[r+1];
            s1[r+2] = ex2(s1[r+2] - m_run); z2 += s1[r+2];
            s1[r+3] = ex2(s1[r+3] - m_run); z3 += s1[r+3];
        }
        l_run += (z0 + z1) + (z2 + z3);   // per-half partial; merged in epilogue

        // ---- pack P, exchange, build K=64 B-frag ----
        // u0/u1 dword m covers tile0/1 j_local 8m+4h+{0..3}
        unsigned u0[4], u1[4], p0[4], p1[4];
        #pragma unroll
        for (int m = 0; m < 4; ++m) {
            u0[m] = pk4fp8(s0[4*m], s0[4*m+1], s0[4*m+2], s0[4*m+3]);
            u1[m] = pk4fp8(s1[4*m], s1[4*m+1], s1[4*m+2], s1[4*m+3]);
        }
        #pragma unroll
        for (int q = 0; q < 4; ++q) {
            p0[q] = (unsigned)__shfl_xor((int)u0[q], 32);
            p1[q] = (unsigned)__shfl_xor((int)u1[q], 32);
        }
        // lane-half h needs tile h: own pack (offsets 4h) + partner pack (4(h^1))
        B8 bf;
        #pragma unroll
        for (int m = 0; m < 4; ++m) {
            unsigned oh = h ? u1[m] : u0[m];
            unsigned ph = h ? p1[m] : p0[m];
            bf.u[2*m]     = h ? ph : oh;   // dword r=2m:   j 8m+0..3
            bf.u[2*m + 1] = h ? oh : ph;   // dword r=2m+1: j 8m+4..7
        }

        // ---- S(n+1): s regs are dead after the pack — reuse them.
        //      Issued BEFORE PV(n) so it completes under PV + next softmax.
        __builtin_amdgcn_s_setprio(1);
        s0 = mfma32(ka1, qf1, mfma32(ka0, qf0, zero16()));
        s1 = mfma32(kb1, qf1, mfma32(kb0, qf0, zero16()));

        // ---- PV(n): 8 MX-scaled K=64 MFMAs ----
        #pragma unroll
        for (int cg = 0; cg < 4; ++cg) acc[cg] = mfma64s(vv[cg].iv, bf.iv, acc[cg]);
        #pragma unroll
        for (int cg = 0; cg < 4; ++cg) {
            vv[cg].q[0] = *(const uint4*)(vp + (cg + 4) * 2048);
            vv[cg].q[1] = *(const uint4*)(vp + (cg + 4) * 2048 + 16);
        }
        #pragma unroll
        for (int cg = 0; cg < 4; ++cg) acc[cg + 4] = mfma64s(vv[cg].iv, bf.iv, acc[cg + 4]);
        __builtin_amdgcn_s_setprio(0);
        vp += 16384;
    }

    // ---- merge the 4 j-quarter waves of each quad (pair) ----
    if (h == 0) mls[w][L] = m_run;
    lls[h][w][L] = l_run;
    __syncthreads();
    const int q4 = pair * 4;
    float m0 = mls[q4 + 0][L], m1 = mls[q4 + 1][L];
    float m2 = mls[q4 + 2][L], m3 = mls[q4 + 3][L];
    float ms = fmaxf(fmaxf(fmaxf(m0, m1), m2), m3);
    float f0 = ex2(m0 - ms), f1 = ex2(m1 - ms);
    float f2 = ex2(m2 - ms), f3 = ex2(m3 - ms);
    float lstar = f0 * (lls[0][q4 + 0][L] + lls[1][q4 + 0][L])
                + f1 * (lls[0][q4 + 1][L] + lls[1][q4 + 1][L])
                + f2 * (lls[0][q4 + 2][L] + lls[1][q4 + 2][L])
                + f3 * (lls[0][q4 + 3][L] + lls[1][q4 + 3][L]);
    const float scale = gamma[0] / lstar;
    const float g0 = scale * f0, g1 = scale * f1;
    const float g2 = scale * f2, g3 = scale * f3;

    const int ti = t & 31, trow = (t >> 5) & 7, quad = t >> 8;
    for (int ck = 0; ck < 4; ++ck) {
        #pragma unroll
        for (int half = 0; half < 2; ++half) {
            #pragma unroll
            for (int r = 0; r < 16; ++r) {
                int prow = (r & 3) + 8 * (r >> 2) + 4 * h;
                obuf[w][half * 1024 + prow * 32 + L] = acc[2 * ck + half][r];
            }
        }
        __syncthreads();
        #pragma unroll
        for (int rr = 0; rr < 8; ++rr) {
            int cr = trow + 8 * rr;
            int idx = cr * 32 + ti;
            float sum = g0 * obuf[quad * 4 + 0][idx] + g1 * obuf[quad * 4 + 1][idx]
                      + g2 * obuf[quad * 4 + 2][idx] + g3 * obuf[quad * 4 + 3][idx];
            size_t gi = ((size_t)b * CC + ck * 64 + cr) * NPIX
                      + it64 * 64 + quad * 32 + ti;
            out[gi] = sum + x[gi];
        }
        __syncthreads();
    }
}

// ---------------------------------------------------------------------------
extern "C" void kernel_launch(void* const* d_in, const int* in_sizes, int n_in,
                              void* d_out, int out_size, void* d_ws, size_t ws_size,
                              hipStream_t stream) {
    const float* x     = (const float*)d_in[0];
    const float* mask  = (const float*)d_in[1];
    const float* Wq    = (const float*)d_in[2];
    const float* bq    = (const float*)d_in[3];
    const float* Wk    = (const float*)d_in[4];
    const float* bk    = (const float*)d_in[5];
    const float* Wv    = (const float*)d_in[6];
    const float* bv    = (const float*)d_in[7];
    const float* gamma = (const float*)d_in[8];
    float* out = (float*)d_out;

    unsigned short* ws = (unsigned short*)d_ws;
    unsigned short* qT = ws;                                   // [B][N][32] bf16
    unsigned short* kT = qT + (size_t)BATCH * NPIX * 32;       // [B][N][32] bf16
    unsigned char*  vI = (unsigned char*)(kT + (size_t)BATCH * NPIX * 32);  // [B][64][8][64][32] fp8
    unsigned short* xpad = (unsigned short*)(vI + (size_t)BATCH * CC * NPIX); // (unused; keeps layout)
    unsigned short* Wfrag = xpad + (size_t)BATCH * NPIX * 256; // [160][64][8] bf16

    prep_w<<<40, 256, 0, stream>>>(Wq, Wk, Wv, Wfrag);
    proj_mfma<<<256, 640, 0, stream>>>(x, Wfrag, mask, bq, bk, bv, qT, kT, vI);
    attn_mfma<<<256, 512, 0, stream>>>(qT, kT, vI, x, gamma, out);
}

// Round 9
// 130.096 us; speedup vs baseline: 1.0006x; 1.0006x over previous
//
#include <hip/hip_runtime.h>
#include <math.h>

#define CC 256
#define NPIX 4096
#define BATCH 4
#define LOG2E 1.4426950408889634f

typedef __attribute__((ext_vector_type(8)))  short short8;
typedef __attribute__((ext_vector_type(8)))  int   int32x8;
typedef __attribute__((ext_vector_type(16))) float f32x16;

union FragU { short8 v; short s[8]; unsigned u[4]; uint2 d[2]; };
union V8  { uint4 q[2]; int32x8 iv; };
union B8  { unsigned u[8]; int32x8 iv; };

__device__ inline unsigned pkbf(float a, float b) {   // pack 2 floats -> 2 bf16 (RNE)
    unsigned x = __float_as_uint(a), y = __float_as_uint(b);
    x = (x + 0x7FFFu + ((x >> 16) & 1u)) >> 16;
    y = (y + 0x7FFFu + ((y >> 16) & 1u)) & 0xFFFF0000u;
    return x | y;
}
__device__ inline unsigned short bf1(float a) {
    unsigned x = __float_as_uint(a);
    return (unsigned short)((x + 0x7FFFu + ((x >> 16) & 1u)) >> 16);
}
__device__ inline float ex2(float x) { return __builtin_amdgcn_exp2f(x); }
__device__ inline unsigned pk4fp8(float a, float b, float c, float d) {
    int r = __builtin_amdgcn_cvt_pk_fp8_f32(a, b, 0, false);
    r = __builtin_amdgcn_cvt_pk_fp8_f32(c, d, r, true);
    return (unsigned)r;
}
__device__ inline f32x16 zero16() {
    f32x16 v;
    #pragma unroll
    for (int i = 0; i < 16; ++i) v[i] = 0.0f;
    return v;
}
__device__ inline f32x16 mfma32(short8 a, short8 b, f32x16 c) {
    return __builtin_amdgcn_mfma_f32_32x32x16_bf16(a, b, c, 0, 0, 0);
}
// MX-scaled fp8 K=64, identity scales (e8m0 0x7F = 2^0)
__device__ inline f32x16 mfma64s(int32x8 a, int32x8 b, f32x16 c) {
    return __builtin_amdgcn_mfma_scale_f32_32x32x64_f8f6f4(
        a, b, c, 0 /*cbsz: fp8*/, 0 /*blgp: fp8*/, 0, 0x7F, 0, 0x7F);
}

// ---------------------------------------------------------------------------
// proj: ONE block per (batch, 64-px tile): 256 blocks x 640 thr (10 waves).
// Phase 0: 512 threads transpose x (f32 [C][N]) into bf16 LDS xls[64][260].
// W fragments are packed DIRECTLY from Wq/Wk/Wv per wave (prep_w kernel
// deleted): lane l of wave ocg needs half of W row oc0+L — 16x 32B loads
// from the 327 KB L2-resident W tensors, bit-identical pkbf packing.
// Wave w = ocg (0=q 1=k 2..9 = V cg) then runs the MFMA projection.
// qT/kT bf16 (q pre-scaled log2e); V written fp8-e4m3 into
// vI[b][j64][cg][lane: jhalf*32+c][32B] (byte = j&31 — K=64 A-frag order).
// ---------------------------------------------------------------------------
__global__ __launch_bounds__(640, 2) void proj_mfma(
    const float* __restrict__ x,
    const float* __restrict__ Wq, const float* __restrict__ Wk,
    const float* __restrict__ Wv,
    const float* __restrict__ mask,
    const float* __restrict__ bq, const float* __restrict__ bk,
    const float* __restrict__ bv,
    unsigned short* __restrict__ qT, unsigned short* __restrict__ kT,
    unsigned char* __restrict__ vI)
{
    __shared__ unsigned short xls[64 * 260];
    const int t = threadIdx.x;
    const int w = t >> 6, l = t & 63, L = l & 31, h = l >> 5;
    const int bid = blockIdx.x;
    const int b    = (bid >> 1) & 3;                 // XCD-pinned by batch
    const int u    = ((bid >> 3) << 1) | (bid & 1);  // 0..63
    const int p0   = u * 64;
    const int ocg  = w;                              // 0=q 1=k 2..9 = v cg

    // ---- phase 0: x -> bf16 LDS transpose (512 threads) ----
    if (t < 512) {
        const int pg = t & 15;               // 4-px group
        const int cb = (t >> 4) * 2;         // channel pair base (0..62 even)
        const float* xb = x + (size_t)b * CC * NPIX + p0 + pg * 4;
        #pragma unroll
        for (int k = 0; k < 4; ++k) {
            int c = cb + 64 * k;
            float4 v0 = *(const float4*)(xb + (size_t)c * NPIX);
            float4 v1 = *(const float4*)(xb + (size_t)(c + 1) * NPIX);
            *(unsigned*)&xls[(pg * 4 + 0) * 260 + c] = pkbf(v0.x, v1.x);
            *(unsigned*)&xls[(pg * 4 + 1) * 260 + c] = pkbf(v0.y, v1.y);
            *(unsigned*)&xls[(pg * 4 + 2) * 260 + c] = pkbf(v0.z, v1.z);
            *(unsigned*)&xls[(pg * 4 + 3) * 260 + c] = pkbf(v0.w, v1.w);
        }
    }

    // ---- W fragment pack (direct from global W; same bits as old prep_w) ----
    const float* wsrc; float wscale = 1.0f; int oc0 = 0;
    if (ocg == 0)      { wsrc = Wq; wscale = LOG2E; }
    else if (ocg == 1) { wsrc = Wk; }
    else               { wsrc = Wv; oc0 = (ocg - 2) * 32; }
    const float* wrow = wsrc + (size_t)(oc0 + L) * CC + 8 * h;
    FragU wf[16];
    #pragma unroll
    for (int s = 0; s < 16; ++s) {
        float4 a = *(const float4*)(wrow + 16 * s);
        float4 c = *(const float4*)(wrow + 16 * s + 4);
        wf[s].u[0] = pkbf(a.x * wscale, a.y * wscale);
        wf[s].u[1] = pkbf(a.z * wscale, a.w * wscale);
        wf[s].u[2] = pkbf(c.x * wscale, c.y * wscale);
        wf[s].u[3] = pkbf(c.z * wscale, c.w * wscale);
    }

    float bcol;
    if (ocg == 0)      bcol = bq[L] * LOG2E;
    else if (ocg == 1) bcol = bk[L];
    else               bcol = bv[(ocg - 2) * 32 + L];
    const float* mb = mask + (size_t)b * NPIX;
    __syncthreads();

    #pragma unroll
    for (int mt = 0; mt < 2; ++mt) {
        const int pp = 32 * mt;
        f32x16 acc = zero16();
        #pragma unroll
        for (int s = 0; s < 16; ++s) {
            FragU af;
            const unsigned short* ap = &xls[(pp + L) * 260 + 16 * s + 8 * h];
            af.d[0] = *(const uint2*)(ap);
            af.d[1] = *(const uint2*)(ap + 4);
            acc = mfma32(af.v, wf[s].v, acc);
        }
        if (ocg < 2) {
            unsigned short* dst = (ocg ? kT : qT) + (size_t)b * NPIX * 32;
            #pragma unroll
            for (int r = 0; r < 16; ++r) {
                int prow = (r & 3) + 8 * (r >> 2) + 4 * h;
                float mv = mb[p0 + pp + prow];
                dst[(size_t)(p0 + pp + prow) * 32 + L] = bf1((acc[r] + bcol) * mv);
            }
        } else {
            const int cg = ocg - 2;
            const int jb32 = p0 + pp;                // 32-j block base
            // dword m holds j-rows 8m+4h+{0..3} -> byte offset 8m+4h
            unsigned char* dst = vI + (size_t)b * (1 << 20)
                + (size_t)(jb32 >> 6) * 16384 + cg * 2048
                + (((jb32 >> 5) & 1) * 32 + L) * 32 + 4 * h;
            #pragma unroll
            for (int m = 0; m < 4; ++m) {
                unsigned pk = pk4fp8(acc[4*m]   + bcol, acc[4*m+1] + bcol,
                                     acc[4*m+2] + bcol, acc[4*m+3] + bcol);
                *(unsigned*)(dst + 8 * m) = pk;
            }
        }
    }
}

// ---------------------------------------------------------------------------
// attn: round-6 verbatim (measured-best). 64-j iters, barrier-free K-loop,
// rotated schedule (Kload(n+1), Vload(n), softmax(n), S(n+1), PV(n)),
// hysteresis 8, per-half l_run merged in epilogue, setprio MFMA clusters.
// ---------------------------------------------------------------------------
__global__ __launch_bounds__(256, 2) void attn_mfma(
    const unsigned short* __restrict__ qT, const unsigned short* __restrict__ kT,
    const unsigned char* __restrict__ vI, const float* __restrict__ x,
    const float* __restrict__ gamma, float* __restrict__ out)
{
    __shared__ float mls[4][32];
    __shared__ float lls[2][4][32];
    __shared__ float obuf[4][2048];

    const int t = threadIdx.x;
    const int w = t >> 6, l = t & 63, L = l & 31, h = l >> 5;
    const int bid = blockIdx.x;
    const int b  = (bid >> 1) & 3;                 // XCD-pinned by batch
    const int it = (bid >> 3) * 2 + (bid & 1);
    const int i0 = it * 32;

    const unsigned short* qrow = qT + ((size_t)b * NPIX + i0 + L) * 32 + 8 * h;
    short8 qf0 = *(const short8*)(qrow);
    short8 qf1 = *(const short8*)(qrow + 16);

    const int jbase = w * 1024;
    // K stream: one byte pointer, advanced 4096 B/iter; imm offsets 0/32/2048/2080
    const unsigned char* kp = (const unsigned char*)kT
        + (size_t)b * NPIX * 64 + (size_t)jbase * 64 + (size_t)L * 64 + 16 * h;
    short8 ka0 = *(const short8*)(kp);
    short8 ka1 = *(const short8*)(kp + 32);
    short8 kb0 = *(const short8*)(kp + 2048);
    short8 kb1 = *(const short8*)(kp + 2080);
    kp += 4096;
    // V stream: lane l reads its 32B at vp + cg*2048; advance 16384 B/iter
    const unsigned char* vp = vI + (size_t)b * (1 << 20)
        + (size_t)(jbase >> 6) * 16384 + (size_t)l * 32;

    f32x16 acc[8];
    #pragma unroll
    for (int cg = 0; cg < 8; ++cg) acc[cg] = zero16();
    float m_run = -INFINITY, l_run = 0.0f;
    bool warm = false;   // first rescale trigger has acc==0: skip the 128-mul pass

    // ---- prologue: S(0) ----
    f32x16 s0 = zero16(), s1 = zero16();
    __builtin_amdgcn_s_setprio(1);
    s0 = mfma32(ka0, qf0, s0);
    s0 = mfma32(ka1, qf1, s0);
    s1 = mfma32(kb0, qf0, s1);
    s1 = mfma32(kb1, qf1, s1);
    __builtin_amdgcn_s_setprio(0);

    for (int itr = 0; itr < 16; ++itr) {
        // ---- K load (n+1) — consumed by S(n+1) at the bottom of THIS iter;
        //      ~500 cyc of softmax VALU covers the L2 latency.
        //      (last iter reads past kT: valid ws mem, result discarded)
        ka0 = *(const short8*)(kp);
        ka1 = *(const short8*)(kp + 32);
        kb0 = *(const short8*)(kp + 2048);
        kb1 = *(const short8*)(kp + 2080);
        kp += 4096;

        // ---- V loads, first half (cg 0..3) ----
        V8 vv[4];
        #pragma unroll
        for (int cg = 0; cg < 4; ++cg) {
            vv[cg].q[0] = *(const uint4*)(vp + cg * 2048);
            vv[cg].q[1] = *(const uint4*)(vp + cg * 2048 + 16);
        }

        // ---- row max: max3 chains, shfl syncs the lane pair (same i) ----
        float t0 = fmaxf(fmaxf(s0[0],  s0[4]),  s0[8]);
        float t1 = fmaxf(fmaxf(s0[1],  s0[5]),  s0[9]);
        float t2 = fmaxf(fmaxf(s0[2],  s0[6]),  s0[10]);
        float t3 = fmaxf(fmaxf(s0[3],  s0[7]),  s0[11]);
        t0 = fmaxf(fmaxf(t0, s0[12]), s1[0]);
        t1 = fmaxf(fmaxf(t1, s0[13]), s1[1]);
        t2 = fmaxf(fmaxf(t2, s0[14]), s1[2]);
        t3 = fmaxf(fmaxf(t3, s0[15]), s1[3]);
        t0 = fmaxf(fmaxf(t0, s1[4]),  s1[8]);
        t1 = fmaxf(fmaxf(t1, s1[5]),  s1[9]);
        t2 = fmaxf(fmaxf(t2, s1[6]),  s1[10]);
        t3 = fmaxf(fmaxf(t3, s1[7]),  s1[11]);
        t0 = fmaxf(t0, s1[12]);
        t1 = fmaxf(t1, s1[13]);
        t2 = fmaxf(t2, s1[14]);
        t3 = fmaxf(t3, s1[15]);
        float tmax = fmaxf(fmaxf(fmaxf(t0, t1), t2), t3);
        tmax = fmaxf(tmax, __shfl_xor(tmax, 32));

        if (__ballot(tmax > m_run + 8.0f)) {
            float m_new = fmaxf(m_run, tmax);
            if (warm) {
                float alpha = ex2(m_run - m_new);
                l_run *= alpha;
                #pragma unroll
                for (int cg = 0; cg < 8; ++cg)
                    #pragma unroll
                    for (int r = 0; r < 16; ++r) acc[cg][r] *= alpha;
            }
            m_run = m_new;
            warm = true;
        }

        float z0 = 0, z1 = 0, z2 = 0, z3 = 0;
        #pragma unroll
        for (int r = 0; r < 16; r += 4) {
            s0[r]   = ex2(s0[r]   - m_run); z0 += s0[r];
            s0[r+1] = ex2(s0[r+1] - m_run); z1 += s0[r+1];
            s0[r+2] = ex2(s0[r+2] - m_run); z2 += s0[r+2];
            s0[r+3] = ex2(s0[r+3] - m_run); z3 += s0[r+3];
        }
        #pragma unroll
        for (int r = 0; r < 16; r += 4) {
            s1[r]   = ex2(s1[r]   - m_run); z0 += s1[r];
            s1[r+1] = ex2(s1[r+1] - m_run); z1 += s1[r+1];
            s1[r+2] = ex2(s1[r+2] - m_run); z2 += s1[r+2];
            s1[r+3] = ex2(s1[r+3] - m_run); z3 += s1[r+3];
        }
        l_run += (z0 + z1) + (z2 + z3);   // per-half partial; merged in epilogue

        // ---- pack P, exchange, build K=64 B-frag ----
        // u0/u1 dword m covers tile0/1 j_local 8m+4h+{0..3}
        unsigned u0[4], u1[4], p0[4], p1[4];
        #pragma unroll
        for (int m = 0; m < 4; ++m) {
            u0[m] = pk4fp8(s0[4*m], s0[4*m+1], s0[4*m+2], s0[4*m+3]);
            u1[m] = pk4fp8(s1[4*m], s1[4*m+1], s1[4*m+2], s1[4*m+3]);
        }
        #pragma unroll
        for (int q = 0; q < 4; ++q) {
            p0[q] = (unsigned)__shfl_xor((int)u0[q], 32);
            p1[q] = (unsigned)__shfl_xor((int)u1[q], 32);
        }
        // lane-half h needs tile h: own pack (offsets 4h) + partner pack (4(h^1))
        B8 bf;
        #pragma unroll
        for (int m = 0; m < 4; ++m) {
            unsigned oh = h ? u1[m] : u0[m];
            unsigned ph = h ? p1[m] : p0[m];
            bf.u[2*m]     = h ? ph : oh;   // dword r=2m:   j 8m+0..3
            bf.u[2*m + 1] = h ? oh : ph;   // dword r=2m+1: j 8m+4..7
        }

        // ---- S(n+1): s regs are dead after the pack — reuse them.
        //      Issued BEFORE PV(n) so it completes under PV + next softmax.
        __builtin_amdgcn_s_setprio(1);
        s0 = mfma32(ka1, qf1, mfma32(ka0, qf0, zero16()));
        s1 = mfma32(kb1, qf1, mfma32(kb0, qf0, zero16()));

        // ---- PV(n): 8 MX-scaled K=64 MFMAs ----
        #pragma unroll
        for (int cg = 0; cg < 4; ++cg) acc[cg] = mfma64s(vv[cg].iv, bf.iv, acc[cg]);
        #pragma unroll
        for (int cg = 0; cg < 4; ++cg) {
            vv[cg].q[0] = *(const uint4*)(vp + (cg + 4) * 2048);
            vv[cg].q[1] = *(const uint4*)(vp + (cg + 4) * 2048 + 16);
        }
        #pragma unroll
        for (int cg = 0; cg < 4; ++cg) acc[cg + 4] = mfma64s(vv[cg].iv, bf.iv, acc[cg + 4]);
        __builtin_amdgcn_s_setprio(0);
        vp += 16384;
    }

    // ---- merge 4 j-quarter waves (f_w folded into the sum — no acc pass) ----
    if (h == 0) mls[w][L] = m_run;
    lls[h][w][L] = l_run;
    __syncthreads();
    float m0 = mls[0][L], m1 = mls[1][L], m2 = mls[2][L], m3 = mls[3][L];
    float ms = fmaxf(fmaxf(fmaxf(m0, m1), m2), m3);
    float f0 = ex2(m0 - ms), f1 = ex2(m1 - ms);
    float f2 = ex2(m2 - ms), f3 = ex2(m3 - ms);
    float lstar = f0 * (lls[0][0][L] + lls[1][0][L])
                + f1 * (lls[0][1][L] + lls[1][1][L])
                + f2 * (lls[0][2][L] + lls[1][2][L])
                + f3 * (lls[0][3][L] + lls[1][3][L]);
    const float scale = gamma[0] / lstar;
    const float g0 = scale * f0, g1 = scale * f1;
    const float g2 = scale * f2, g3 = scale * f3;

    const int ti = t & 31, trow = t >> 5;
    for (int ck = 0; ck < 4; ++ck) {
        #pragma unroll
        for (int half = 0; half < 2; ++half) {
            #pragma unroll
            for (int r = 0; r < 16; ++r) {
                int prow = (r & 3) + 8 * (r >> 2) + 4 * h;
                obuf[w][half * 1024 + prow * 32 + L] = acc[2 * ck + half][r];
            }
        }
        __syncthreads();
        #pragma unroll
        for (int rr = 0; rr < 8; ++rr) {
            int cr = trow + 8 * rr;
            int idx = cr * 32 + ti;
            float sum = g0 * obuf[0][idx] + g1 * obuf[1][idx]
                      + g2 * obuf[2][idx] + g3 * obuf[3][idx];
            size_t gi = ((size_t)b * CC + ck * 64 + cr) * NPIX + i0 + ti;
            out[gi] = sum + x[gi];
        }
        __syncthreads();
    }
}

// ---------------------------------------------------------------------------
extern "C" void kernel_launch(void* const* d_in, const int* in_sizes, int n_in,
                              void* d_out, int out_size, void* d_ws, size_t ws_size,
                              hipStream_t stream) {
    const float* x     = (const float*)d_in[0];
    const float* mask  = (const float*)d_in[1];
    const float* Wq    = (const float*)d_in[2];
    const float* bq    = (const float*)d_in[3];
    const float* Wk    = (const float*)d_in[4];
    const float* bk    = (const float*)d_in[5];
    const float* Wv    = (const float*)d_in[6];
    const float* bv    = (const float*)d_in[7];
    const float* gamma = (const float*)d_in[8];
    float* out = (float*)d_out;

    unsigned short* ws = (unsigned short*)d_ws;
    unsigned short* qT = ws;                                   // [B][N][32] bf16
    unsigned short* kT = qT + (size_t)BATCH * NPIX * 32;       // [B][N][32] bf16
    unsigned char*  vI = (unsigned char*)(kT + (size_t)BATCH * NPIX * 32);  // [B][64][8][64][32] fp8

    proj_mfma<<<256, 640, 0, stream>>>(x, Wq, Wk, Wv, mask, bq, bk, bv, qT, kT, vI);
    attn_mfma<<<512, 256, 0, stream>>>(qT, kT, vI, x, gamma, out);
}

// Round 10
// 122.168 us; speedup vs baseline: 1.0655x; 1.0649x over previous
//
#include <hip/hip_runtime.h>
#include <math.h>

#define CC 256
#define NPIX 4096
#define BATCH 4
#define LOG2E 1.4426950408889634f

typedef __attribute__((ext_vector_type(8)))  short short8;
typedef __attribute__((ext_vector_type(8)))  int   int32x8;
typedef __attribute__((ext_vector_type(16))) float f32x16;

union FragU { short8 v; short s[8]; unsigned u[4]; uint2 d[2]; };
union V8  { uint4 q[2]; int32x8 iv; };
union B8  { unsigned u[8]; int32x8 iv; };

__device__ inline unsigned pkbf(float a, float b) {   // pack 2 floats -> 2 bf16 (RNE)
    unsigned x = __float_as_uint(a), y = __float_as_uint(b);
    x = (x + 0x7FFFu + ((x >> 16) & 1u)) >> 16;
    y = (y + 0x7FFFu + ((y >> 16) & 1u)) & 0xFFFF0000u;
    return x | y;
}
__device__ inline unsigned short bf1(float a) {
    unsigned x = __float_as_uint(a);
    return (unsigned short)((x + 0x7FFFu + ((x >> 16) & 1u)) >> 16);
}
__device__ inline float ex2(float x) { return __builtin_amdgcn_exp2f(x); }
__device__ inline unsigned pk4fp8(float a, float b, float c, float d) {
    int r = __builtin_amdgcn_cvt_pk_fp8_f32(a, b, 0, false);
    r = __builtin_amdgcn_cvt_pk_fp8_f32(c, d, r, true);
    return (unsigned)r;
}
__device__ inline f32x16 zero16() {
    f32x16 v;
    #pragma unroll
    for (int i = 0; i < 16; ++i) v[i] = 0.0f;
    return v;
}
__device__ inline f32x16 mfma32(short8 a, short8 b, f32x16 c) {
    return __builtin_amdgcn_mfma_f32_32x32x16_bf16(a, b, c, 0, 0, 0);
}
// MX-scaled fp8 K=64, identity scales (e8m0 0x7F = 2^0)
__device__ inline f32x16 mfma64s(int32x8 a, int32x8 b, f32x16 c) {
    return __builtin_amdgcn_mfma_scale_f32_32x32x64_f8f6f4(
        a, b, c, 0 /*cbsz: fp8*/, 0 /*blgp: fp8*/, 0, 0x7F, 0, 0x7F);
}

// ---------------------------------------------------------------------------
// prep_w: 40 blocks, W-pack only (the x-transpose lives in proj).
// Packs W -> Wfrag[gs][lane][8] in MFMA B-frag order. Kept as a separate
// kernel: round-9 measured that per-block inline W packing (64-lane scatters
// with 1 KB stride on proj's serial pre-barrier path) costs ~6 us more than
// this one coalesced pre-pack + launch.
// ---------------------------------------------------------------------------
__global__ __launch_bounds__(256, 2) void prep_w(
    const float* __restrict__ Wq, const float* __restrict__ Wk,
    const float* __restrict__ Wv, unsigned short* __restrict__ Wfrag)
{
    const int t = threadIdx.x;
    const int wb = blockIdx.x;           // 0..39
    const int l = t & 63, rr = t >> 6;   // rr 0..3
    #pragma unroll
    for (int e = 0; e < 4; ++e) {
        int gs = wb * 4 + e;             // 0..159
        int g = gs >> 4, s = gs & 15;
        const float* src; float scale = 1.0f; int oc0 = 0;
        if (g == 0)      { src = Wq; scale = LOG2E; }
        else if (g == 1) { src = Wk; }
        else             { src = Wv; oc0 = (g - 2) * 32; }
        int row = oc0 + (l & 31);
        int kb2 = 16 * s + 8 * (l >> 5) + rr * 2;
        float v0 = src[(size_t)row * CC + kb2] * scale;
        float v1 = src[(size_t)row * CC + kb2 + 1] * scale;
        *(unsigned*)(Wfrag + (size_t)(gs * 64 + l) * 8 + rr * 2) = pkbf(v0, v1);
    }
}

// ---------------------------------------------------------------------------
// proj: ONE block per (batch, 64-px tile): 256 blocks x 640 thr (10 waves).
// Phase 0: 512 threads transpose x (f32 [C][N]) directly into the bf16 LDS
// tile xls[p][c]. Then wave w = ocg (0=q 1=k 2..9 = V channel groups) runs
// the MFMA projection. qT/kT bf16 (q pre-scaled log2e); V written fp8-e4m3
// into vI[b][j64][cg][lane: jhalf*32+c][32B] (byte = j&31 — K=64 A-frag).
// (64-px tile at grid 256 measured faster than the 32-px/grid-512 split.)
// ---------------------------------------------------------------------------
__global__ __launch_bounds__(640, 2) void proj_mfma(
    const float* __restrict__ x, const unsigned short* __restrict__ Wfrag,
    const float* __restrict__ mask,
    const float* __restrict__ bq, const float* __restrict__ bk,
    const float* __restrict__ bv,
    unsigned short* __restrict__ qT, unsigned short* __restrict__ kT,
    unsigned char* __restrict__ vI)
{
    __shared__ unsigned short xls[64 * 260];
    const int t = threadIdx.x;
    const int w = t >> 6, l = t & 63, L = l & 31, h = l >> 5;
    const int bid = blockIdx.x;
    const int b    = (bid >> 1) & 3;                 // XCD-pinned by batch
    const int u    = ((bid >> 3) << 1) | (bid & 1);  // 0..63
    const int p0   = u * 64;
    const int ocg  = w;                              // 0=q 1=k 2..9 = v cg

    // ---- phase 0: x -> bf16 LDS transpose (512 threads) ----
    if (t < 512) {
        const int pg = t & 15;               // 4-px group
        const int cb = (t >> 4) * 2;         // channel pair base (0..62 even)
        const float* xb = x + (size_t)b * CC * NPIX + p0 + pg * 4;
        #pragma unroll
        for (int k = 0; k < 4; ++k) {
            int c = cb + 64 * k;
            float4 v0 = *(const float4*)(xb + (size_t)c * NPIX);
            float4 v1 = *(const float4*)(xb + (size_t)(c + 1) * NPIX);
            *(unsigned*)&xls[(pg * 4 + 0) * 260 + c] = pkbf(v0.x, v1.x);
            *(unsigned*)&xls[(pg * 4 + 1) * 260 + c] = pkbf(v0.y, v1.y);
            *(unsigned*)&xls[(pg * 4 + 2) * 260 + c] = pkbf(v0.z, v1.z);
            *(unsigned*)&xls[(pg * 4 + 3) * 260 + c] = pkbf(v0.w, v1.w);
        }
    }

    FragU wf[16];
    const unsigned short* wp = Wfrag + (size_t)(ocg * 16 * 64 + l) * 8;
    #pragma unroll
    for (int s = 0; s < 16; ++s) wf[s].v = *(const short8*)(wp + s * 512);

    float bcol;
    if (ocg == 0)      bcol = bq[L] * LOG2E;
    else if (ocg == 1) bcol = bk[L];
    else               bcol = bv[(ocg - 2) * 32 + L];
    const float* mb = mask + (size_t)b * NPIX;
    __syncthreads();

    #pragma unroll
    for (int mt = 0; mt < 2; ++mt) {
        const int pp = 32 * mt;
        f32x16 acc = zero16();
        #pragma unroll
        for (int s = 0; s < 16; ++s) {
            FragU af;
            const unsigned short* ap = &xls[(pp + L) * 260 + 16 * s + 8 * h];
            af.d[0] = *(const uint2*)(ap);
            af.d[1] = *(const uint2*)(ap + 4);
            acc = mfma32(af.v, wf[s].v, acc);
        }
        if (ocg < 2) {
            unsigned short* dst = (ocg ? kT : qT) + (size_t)b * NPIX * 32;
            #pragma unroll
            for (int r = 0; r < 16; ++r) {
                int prow = (r & 3) + 8 * (r >> 2) + 4 * h;
                float mv = mb[p0 + pp + prow];
                dst[(size_t)(p0 + pp + prow) * 32 + L] = bf1((acc[r] + bcol) * mv);
            }
        } else {
            const int cg = ocg - 2;
            const int jb32 = p0 + pp;                // 32-j block base
            // dword m holds j-rows 8m+4h+{0..3} -> byte offset 8m+4h
            unsigned char* dst = vI + (size_t)b * (1 << 20)
                + (size_t)(jb32 >> 6) * 16384 + cg * 2048
                + (((jb32 >> 5) & 1) * 32 + L) * 32 + 4 * h;
            #pragma unroll
            for (int m = 0; m < 4; ++m) {
                unsigned pk = pk4fp8(acc[4*m]   + bcol, acc[4*m+1] + bcol,
                                     acc[4*m+2] + bcol, acc[4*m+3] + bcol);
                *(unsigned*)(dst + 8 * m) = pk;
            }
        }
    }
}

// ---------------------------------------------------------------------------
// attn: 64-j iters, barrier-free K-loop, wave-local exp2-domain online softmax.
// Schedule rotated for intra-wave MFMA/VALU overlap:
//   per iter: Kload(n+1), Vload(n), SOFTMAX(n), S(n+1) [reuses s regs],
//   PV(n) — so PV(n) executes under softmax(n+1)'s VALU chain and S(n+1)
//   is done before its consumer. Hysteresis 8 (fp8 max 448 >> 2^8).
// l_run kept per lane-half; combined in the epilogue (no per-iter shfl).
// Measured-best attn variant (round 6). 8-wave fusion with per-iter barrier
// REGRESSED (+4 us despite lower L2 traffic): latency-bound, not BW-bound.
// ---------------------------------------------------------------------------
__global__ __launch_bounds__(256, 2) void attn_mfma(
    const unsigned short* __restrict__ qT, const unsigned short* __restrict__ kT,
    const unsigned char* __restrict__ vI, const float* __restrict__ x,
    const float* __restrict__ gamma, float* __restrict__ out)
{
    __shared__ float mls[4][32];
    __shared__ float lls[2][4][32];
    __shared__ float obuf[4][2048];

    const int t = threadIdx.x;
    const int w = t >> 6, l = t & 63, L = l & 31, h = l >> 5;
    const int bid = blockIdx.x;
    const int b  = (bid >> 1) & 3;                 // XCD-pinned by batch
    const int it = (bid >> 3) * 2 + (bid & 1);
    const int i0 = it * 32;

    const unsigned short* qrow = qT + ((size_t)b * NPIX + i0 + L) * 32 + 8 * h;
    short8 qf0 = *(const short8*)(qrow);
    short8 qf1 = *(const short8*)(qrow + 16);

    const int jbase = w * 1024;
    // K stream: one byte pointer, advanced 4096 B/iter; imm offsets 0/32/2048/2080
    const unsigned char* kp = (const unsigned char*)kT
        + (size_t)b * NPIX * 64 + (size_t)jbase * 64 + (size_t)L * 64 + 16 * h;
    short8 ka0 = *(const short8*)(kp);
    short8 ka1 = *(const short8*)(kp + 32);
    short8 kb0 = *(const short8*)(kp + 2048);
    short8 kb1 = *(const short8*)(kp + 2080);
    kp += 4096;
    // V stream: lane l reads its 32B at vp + cg*2048; advance 16384 B/iter
    const unsigned char* vp = vI + (size_t)b * (1 << 20)
        + (size_t)(jbase >> 6) * 16384 + (size_t)l * 32;

    f32x16 acc[8];
    #pragma unroll
    for (int cg = 0; cg < 8; ++cg) acc[cg] = zero16();
    float m_run = -INFINITY, l_run = 0.0f;
    bool warm = false;   // first rescale trigger has acc==0: skip the 128-mul pass

    // ---- prologue: S(0) ----
    f32x16 s0 = zero16(), s1 = zero16();
    __builtin_amdgcn_s_setprio(1);
    s0 = mfma32(ka0, qf0, s0);
    s0 = mfma32(ka1, qf1, s0);
    s1 = mfma32(kb0, qf0, s1);
    s1 = mfma32(kb1, qf1, s1);
    __builtin_amdgcn_s_setprio(0);

    for (int itr = 0; itr < 16; ++itr) {
        // ---- K load (n+1) — consumed by S(n+1) at the bottom of THIS iter;
        //      ~500 cyc of softmax VALU covers the L2 latency.
        //      (last iter reads past kT: valid ws mem, result discarded)
        ka0 = *(const short8*)(kp);
        ka1 = *(const short8*)(kp + 32);
        kb0 = *(const short8*)(kp + 2048);
        kb1 = *(const short8*)(kp + 2080);
        kp += 4096;

        // ---- V loads, first half (cg 0..3) ----
        V8 vv[4];
        #pragma unroll
        for (int cg = 0; cg < 4; ++cg) {
            vv[cg].q[0] = *(const uint4*)(vp + cg * 2048);
            vv[cg].q[1] = *(const uint4*)(vp + cg * 2048 + 16);
        }

        // ---- row max: max3 chains, shfl syncs the lane pair (same i) ----
        float t0 = fmaxf(fmaxf(s0[0],  s0[4]),  s0[8]);
        float t1 = fmaxf(fmaxf(s0[1],  s0[5]),  s0[9]);
        float t2 = fmaxf(fmaxf(s0[2],  s0[6]),  s0[10]);
        float t3 = fmaxf(fmaxf(s0[3],  s0[7]),  s0[11]);
        t0 = fmaxf(fmaxf(t0, s0[12]), s1[0]);
        t1 = fmaxf(fmaxf(t1, s0[13]), s1[1]);
        t2 = fmaxf(fmaxf(t2, s0[14]), s1[2]);
        t3 = fmaxf(fmaxf(t3, s0[15]), s1[3]);
        t0 = fmaxf(fmaxf(t0, s1[4]),  s1[8]);
        t1 = fmaxf(fmaxf(t1, s1[5]),  s1[9]);
        t2 = fmaxf(fmaxf(t2, s1[6]),  s1[10]);
        t3 = fmaxf(fmaxf(t3, s1[7]),  s1[11]);
        t0 = fmaxf(t0, s1[12]);
        t1 = fmaxf(t1, s1[13]);
        t2 = fmaxf(t2, s1[14]);
        t3 = fmaxf(t3, s1[15]);
        float tmax = fmaxf(fmaxf(fmaxf(t0, t1), t2), t3);
        tmax = fmaxf(tmax, __shfl_xor(tmax, 32));

        if (__ballot(tmax > m_run + 8.0f)) {
            float m_new = fmaxf(m_run, tmax);
            if (warm) {
                float alpha = ex2(m_run - m_new);
                l_run *= alpha;
                #pragma unroll
                for (int cg = 0; cg < 8; ++cg)
                    #pragma unroll
                    for (int r = 0; r < 16; ++r) acc[cg][r] *= alpha;
            }
            m_run = m_new;
            warm = true;
        }

        float z0 = 0, z1 = 0, z2 = 0, z3 = 0;
        #pragma unroll
        for (int r = 0; r < 16; r += 4) {
            s0[r]   = ex2(s0[r]   - m_run); z0 += s0[r];
            s0[r+1] = ex2(s0[r+1] - m_run); z1 += s0[r+1];
            s0[r+2] = ex2(s0[r+2] - m_run); z2 += s0[r+2];
            s0[r+3] = ex2(s0[r+3] - m_run); z3 += s0[r+3];
        }
        #pragma unroll
        for (int r = 0; r < 16; r += 4) {
            s1[r]   = ex2(s1[r]   - m_run); z0 += s1[r];
            s1[r+1] = ex2(s1[r+1] - m_run); z1 += s1[r+1];
            s1[r+2] = ex2(s1[r+2] - m_run); z2 += s1[r+2];
            s1[r+3] = ex2(s1[r+3] - m_run); z3 += s1[r+3];
        }
        l_run += (z0 + z1) + (z2 + z3);   // per-half partial; merged in epilogue

        // ---- pack P, exchange, build K=64 B-frag ----
        // u0/u1 dword m covers tile0/1 j_local 8m+4h+{0..3}
        unsigned u0[4], u1[4], p0[4], p1[4];
        #pragma unroll
        for (int m = 0; m < 4; ++m) {
            u0[m] = pk4fp8(s0[4*m], s0[4*m+1], s0[4*m+2], s0[4*m+3]);
            u1[m] = pk4fp8(s1[4*m], s1[4*m+1], s1[4*m+2], s1[4*m+3]);
        }
        #pragma unroll
        for (int q = 0; q < 4; ++q) {
            p0[q] = (unsigned)__shfl_xor((int)u0[q], 32);
            p1[q] = (unsigned)__shfl_xor((int)u1[q], 32);
        }
        // lane-half h needs tile h: own pack (offsets 4h) + partner pack (4(h^1))
        B8 bf;
        #pragma unroll
        for (int m = 0; m < 4; ++m) {
            unsigned oh = h ? u1[m] : u0[m];
            unsigned ph = h ? p1[m] : p0[m];
            bf.u[2*m]     = h ? ph : oh;   // dword r=2m:   j 8m+0..3
            bf.u[2*m + 1] = h ? oh : ph;   // dword r=2m+1: j 8m+4..7
        }

        // ---- S(n+1): s regs are dead after the pack — reuse them.
        //      Issued BEFORE PV(n) so it completes under PV + next softmax.
        __builtin_amdgcn_s_setprio(1);
        s0 = mfma32(ka1, qf1, mfma32(ka0, qf0, zero16()));
        s1 = mfma32(kb1, qf1, mfma32(kb0, qf0, zero16()));

        // ---- PV(n): 8 MX-scaled K=64 MFMAs ----
        #pragma unroll
        for (int cg = 0; cg < 4; ++cg) acc[cg] = mfma64s(vv[cg].iv, bf.iv, acc[cg]);
        #pragma unroll
        for (int cg = 0; cg < 4; ++cg) {
            vv[cg].q[0] = *(const uint4*)(vp + (cg + 4) * 2048);
            vv[cg].q[1] = *(const uint4*)(vp + (cg + 4) * 2048 + 16);
        }
        #pragma unroll
        for (int cg = 0; cg < 4; ++cg) acc[cg + 4] = mfma64s(vv[cg].iv, bf.iv, acc[cg + 4]);
        __builtin_amdgcn_s_setprio(0);
        vp += 16384;
    }

    // ---- merge 4 j-quarter waves (f_w folded into the sum — no acc pass) ----
    if (h == 0) mls[w][L] = m_run;
    lls[h][w][L] = l_run;
    __syncthreads();
    float m0 = mls[0][L], m1 = mls[1][L], m2 = mls[2][L], m3 = mls[3][L];
    float ms = fmaxf(fmaxf(fmaxf(m0, m1), m2), m3);
    float f0 = ex2(m0 - ms), f1 = ex2(m1 - ms);
    float f2 = ex2(m2 - ms), f3 = ex2(m3 - ms);
    float lstar = f0 * (lls[0][0][L] + lls[1][0][L])
                + f1 * (lls[0][1][L] + lls[1][1][L])
                + f2 * (lls[0][2][L] + lls[1][2][L])
                + f3 * (lls[0][3][L] + lls[1][3][L]);
    const float scale = gamma[0] / lstar;
    const float g0 = scale * f0, g1 = scale * f1;
    const float g2 = scale * f2, g3 = scale * f3;

    const int ti = t & 31, trow = t >> 5;
    for (int ck = 0; ck < 4; ++ck) {
        #pragma unroll
        for (int half = 0; half < 2; ++half) {
            #pragma unroll
            for (int r = 0; r < 16; ++r) {
                int prow = (r & 3) + 8 * (r >> 2) + 4 * h;
                obuf[w][half * 1024 + prow * 32 + L] = acc[2 * ck + half][r];
            }
        }
        __syncthreads();
        #pragma unroll
        for (int rr = 0; rr < 8; ++rr) {
            int cr = trow + 8 * rr;
            int idx = cr * 32 + ti;
            float sum = g0 * obuf[0][idx] + g1 * obuf[1][idx]
                      + g2 * obuf[2][idx] + g3 * obuf[3][idx];
            size_t gi = ((size_t)b * CC + ck * 64 + cr) * NPIX + i0 + ti;
            out[gi] = sum + x[gi];
        }
        __syncthreads();
    }
}

// ---------------------------------------------------------------------------
extern "C" void kernel_launch(void* const* d_in, const int* in_sizes, int n_in,
                              void* d_out, int out_size, void* d_ws, size_t ws_size,
                              hipStream_t stream) {
    const float* x     = (const float*)d_in[0];
    const float* mask  = (const float*)d_in[1];
    const float* Wq    = (const float*)d_in[2];
    const float* bq    = (const float*)d_in[3];
    const float* Wk    = (const float*)d_in[4];
    const float* bk    = (const float*)d_in[5];
    const float* Wv    = (const float*)d_in[6];
    const float* bv    = (const float*)d_in[7];
    const float* gamma = (const float*)d_in[8];
    float* out = (float*)d_out;

    unsigned short* ws = (unsigned short*)d_ws;
    unsigned short* qT = ws;                                   // [B][N][32] bf16
    unsigned short* kT = qT + (size_t)BATCH * NPIX * 32;       // [B][N][32] bf16
    unsigned char*  vI = (unsigned char*)(kT + (size_t)BATCH * NPIX * 32);  // [B][64][8][64][32] fp8
    unsigned short* xpad = (unsigned short*)(vI + (size_t)BATCH * CC * NPIX); // (unused; keeps layout)
    unsigned short* Wfrag = xpad + (size_t)BATCH * NPIX * 256; // [160][64][8] bf16

    prep_w<<<40, 256, 0, stream>>>(Wq, Wk, Wv, Wfrag);
    proj_mfma<<<256, 640, 0, stream>>>(x, Wfrag, mask, bq, bk, bv, qT, kT, vI);
    attn_mfma<<<512, 256, 0, stream>>>(qT, kT, vI, x, gamma, out);
}